// Round 10
// baseline (293.010 us; speedup 1.0000x reference)
//
#include <hip/hip_runtime.h>
#include <hip/hip_bf16.h>

#define NPP 4096
#define BB 4
#define NQ 4
#define CAP 160
#define MOSTRIDE 66

typedef float f32x2 __attribute__((ext_vector_type(2)));
typedef unsigned long long u64;

// packed fp32 fma: d = a*b + c elementwise on a 2-wide register pair.
__device__ __forceinline__ f32x2 pk_fma(f32x2 a, f32x2 b, f32x2 c) {
    f32x2 d;
    asm("v_pk_fma_f32 %0, %1, %2, %3" : "=v"(d) : "v"(a), "v"(b), "v"(c));
    return d;
}

template <typename T>
__device__ __forceinline__ T bitonic_sort64(T v, int lane) {
    #pragma unroll
    for (int k = 2; k <= 64; k <<= 1) {
        #pragma unroll
        for (int j = k >> 1; j > 0; j >>= 1) {
            T p = __shfl_xor(v, j);
            bool up  = ((lane & k) == 0);
            bool low = ((lane & j) == 0);
            T mn = (v < p) ? v : p;
            T mx = (v < p) ? p : v;
            v = (up == low) ? mn : mx;
        }
    }
    return v;
}

// dot8 via 4 packed fmas + horizontal add. Deterministic expression tree:
// identical in pass A and pass B -> identical key bits.
__device__ __forceinline__ float dot8_pk(const f32x2* qp, float4 A0, float4 A1) {
    f32x2 p0 = {A0.x, A0.y}, p1 = {A0.z, A0.w};
    f32x2 p2 = {A1.x, A1.y}, p3 = {A1.z, A1.w};
    f32x2 acc = {0.f, 0.f};
    acc = pk_fma(qp[0], p0, acc);
    acc = pk_fma(qp[1], p1, acc);
    acc = pk_fma(qp[2], p2, acc);
    acc = pk_fma(qp[3], p3, acc);
    return acc.x + acc.y;
}

// ---------- kernel 0: squared norms + z projections + zero zout ----------

__global__ __launch_bounds__(256) void n2_kernel(
    const float* __restrict__ x, const float* __restrict__ z,
    const float* __restrict__ Wmz, const float* __restrict__ bmz,
    const float* __restrict__ Wvz, const float* __restrict__ bvz,
    float* __restrict__ n2tab, float* __restrict__ zzm, float* __restrict__ zzv,
    float* __restrict__ zout)
{
    int i = blockIdx.x * 256 + threadIdx.x;       // 0..16383
    const float4* p = (const float4*)(x + (long)i * 8);
    float4 a = p[0], c = p[1];
    float s = 0.f;
    s = fmaf(a.x, a.x, s); s = fmaf(a.y, a.y, s);
    s = fmaf(a.z, a.z, s); s = fmaf(a.w, a.w, s);
    s = fmaf(c.x, c.x, s); s = fmaf(c.y, c.y, s);
    s = fmaf(c.z, c.z, s); s = fmaf(c.w, c.w, s);
    n2tab[i] = s;

    if (blockIdx.x == 0) {
        zout[threadIdx.x] = 0.f;                  // 256 floats
        int b = threadIdx.x >> 6, l = threadIdx.x & 63;
        float sv = 0.f;
        for (int q = 0; q < 64; ++q) sv = fmaf(z[b * 64 + q], Wvz[q * 64 + l], sv);
        zzv[b * 64 + l] = sv + bvz[l];
        if (threadIdx.x < 32) {
            int bm = threadIdx.x >> 3, lm = threadIdx.x & 7;
            float sm = 0.f;
            for (int q = 0; q < 64; ++q) sm = fmaf(z[bm * 64 + q], Wmz[q * 8 + lm], sm);
            zzm[bm * 8 + lm] = sm + bmz[lm];
        }
    }
}

// ---------- fused kernel: 2-wave team knn + features ----------
// Block = 2 waves sharing 4 queries. Wave w owns candidate half
// t in [32w, 32w+32). Pass A: half-sampled own half (16 iters, 64 disjoint
// 16-cand substreams) -> T_w = 16th smallest of 64 lane minima. T_w has 16
// in-half witnesses <= T_w, so global-16th <= T_w -> every true top-16 key
// <= T_w for both waves -> own-threshold appends form a superset of the
// exact top-16. Pass B: full own half, append (key<<32)|j to the shared
// per-q buffer. After a barrier each wave sorts 2 queries (u64 bitonic +
// chunk merge), gathers its 2 points, and runs the feature pipeline.

__global__ __launch_bounds__(128) void fused_kernel(
    const float* __restrict__ x, const float* __restrict__ n2tab,
    const float* __restrict__ Wm2, const float* __restrict__ bm2,
    const float* __restrict__ Wm3, const float* __restrict__ bm3,
    const float* __restrict__ Wv2, const float* __restrict__ bv2,
    const float* __restrict__ Wv3, const float* __restrict__ bv3,
    const float* __restrict__ Wmx, const float* __restrict__ bmx,
    const float* __restrict__ Wvx, const float* __restrict__ bvx,
    const float* __restrict__ zzm, const float* __restrict__ zzv,
    float* __restrict__ xout, float* __restrict__ zout)
{
    // union: cand u64[4][CAP] (5120B) then mo float[2][15][66] (7920B)
    __shared__ __align__(16) char ubuf[7936];
    __shared__ float xg_s[2][2][16][8];       // [wave][sub][nbr][feat] 2 KB
    __shared__ float wmxT_s[8][36];           // Wmx transposed
    __shared__ float bzm_s[8];
    __shared__ unsigned cnt_s[NQ];

    int lane = threadIdx.x & 63;
    int wid2 = threadIdx.x >> 6;              // 0..1
    int q0   = blockIdx.x * NQ;               // 4 queries per block
    int b    = q0 >> 12;
    int qloc = q0 & 4095;
    const float* xb = x + (long)b * NPP * 8;
    const float* nb = n2tab + b * NPP;

    for (int i = threadIdx.x; i < 256; i += 128)
        wmxT_s[i & 7][i >> 3] = Wmx[i];
    if (threadIdx.x < 8) bzm_s[threadIdx.x] = bmx[threadIdx.x] + zzm[b * 8 + threadIdx.x];
    if (threadIdx.x < NQ) cnt_s[threadIdx.x] = 0;

    // ---- queries ----
    f32x2 qp[NQ][4];
    float n2i[NQ];
    int selfT[NQ], selfL[NQ];
    #pragma unroll
    for (int q = 0; q < NQ; ++q) {
        const f32x2* qsrc = (const f32x2*)(xb + (long)(qloc + q) * 8);
        #pragma unroll
        for (int e = 0; e < 4; ++e) qp[q][e] = qsrc[e];
        n2i[q]   = nb[qloc + q];
        selfT[q] = (qloc + q) >> 6;
        selfL[q] = (qloc + q) & 63;
    }

    __syncthreads();                          // cnt_s init visible

    int tbase = wid2 * 32;                    // own candidate half

    // ---- pass A: half-sampled own half ----
    unsigned minb[NQ];
    #pragma unroll
    for (int q = 0; q < NQ; ++q) minb[q] = 0xFFFFFFFFu;

    #pragma unroll 4
    for (int i = 0; i < 16; ++i) {
        int t = tbase + (i << 1);
        int j = t * 64 + lane;
        const float4* pj = (const float4*)(xb + (long)j * 8);
        float4 A0 = pj[0], A1 = pj[1];
        float n2j = nb[j];
        #pragma unroll
        for (int q = 0; q < NQ; ++q) {
            float dot = dot8_pk(qp[q], A0, A1);
            float d2  = fmaf(-2.0f, dot, n2i[q] + n2j);
            unsigned kb = __float_as_uint(d2);       // d2<0 -> >=0x80000000
            if (t == selfT[q]) kb = (lane == selfL[q]) ? 0xFFFFFFFFu : kb;
            minb[q] = (kb < minb[q]) ? kb : minb[q];
        }
    }

    unsigned T[NQ];
    #pragma unroll
    for (int q = 0; q < NQ; ++q) {
        unsigned s = bitonic_sort64(minb[q], lane);
        T[q] = (unsigned)__shfl((int)s, 15);
    }

    // ---- pass B: full own half + rare atomic append ----
    u64* cand = (u64*)ubuf;                   // [q*CAP + i]
    #pragma unroll 4
    for (int i = 0; i < 32; ++i) {
        int t = tbase + i;
        int j = t * 64 + lane;
        const float4* pj = (const float4*)(xb + (long)j * 8);
        float4 A0 = pj[0], A1 = pj[1];
        float n2j = nb[j];
        #pragma unroll
        for (int q = 0; q < NQ; ++q) {
            float dot = dot8_pk(qp[q], A0, A1);
            float d2  = fmaf(-2.0f, dot, n2i[q] + n2j);
            unsigned kb = __float_as_uint(d2);
            if (t == selfT[q]) kb = (lane == selfL[q]) ? 0xFFFFFFFFu : kb;
            if (kb <= T[q]) {
                unsigned old = atomicAdd(&cnt_s[q], 1u);
                if (old < CAP) cand[q * CAP + old] = ((u64)kb << 32) | (unsigned)j;
            }
        }
    }

    __syncthreads();                          // all appends visible

    // ---- each wave: sort + gather its 2 queries ----
    #pragma unroll 1
    for (int sub = 0; sub < 2; ++sub) {
        int qs = wid2 * 2 + sub;
        unsigned nc = cnt_s[qs];
        int n = nc > CAP ? CAP : (int)nc;
        u64 v = (lane < n) ? cand[qs * CAP + lane] : ~0ull;
        u64 R = bitonic_sort64(v, lane);
        int nch = (n + 63) >> 6;
        #pragma unroll 1
        for (int c2 = 1; c2 < nch; ++c2) {
            int base = c2 << 6;
            u64 w2 = (base + lane < n) ? cand[qs * CAP + base + lane] : ~0ull;
            w2 = bitonic_sort64(w2, lane);
            u64 vt = __shfl(w2, lane - 16);
            u64 comb = (lane < 16) ? R : ((lane < 32) ? vt : ~0ull);
            R = bitonic_sort64(comb, lane);
        }
        if (lane < 16) {                      // gather issued immediately
            int id = (int)(R & 0xFFFFFFFFull);
            const float4* ps = (const float4*)(xb + (long)id * 8);
            float4 A = ps[0], C = ps[1];
            *((float4*)&xg_s[wid2][sub][lane][0]) = A;
            *((float4*)&xg_s[wid2][sub][lane][4]) = C;
        }
    }

    __syncthreads();                          // cand dead -> mo may alias

    // ---- feature weights ----
    int k = lane & 15;
    float w20 = Wm2[k], w21 = Wm2[16 + k], bb2 = bm2[k];
    float w30 = Wm3[k], w31 = Wm3[16 + k], w32 = Wm3[32 + k], bb3 = bm3[k];
    float u20 = Wv2[k], u21 = Wv2[16 + k], cc2 = bv2[k];
    float u30 = Wv3[k], u31 = Wv3[16 + k], u32 = Wv3[32 + k], cc3 = bv3[k];

    int g  = lane >> 5;
    int nm = lane & 31;
    f32x2 wa2[16], wb2[16];
    #pragma unroll
    for (int cc = 0; cc < 16; ++cc) {
        wa2[cc].x = Wvx[(2 * cc) * 64 + nm];
        wa2[cc].y = Wvx[(2 * cc + 1) * 64 + nm];
        wb2[cc].x = Wvx[(2 * cc) * 64 + nm + 32];
        wb2[cc].y = Wvx[(2 * cc + 1) * 64 + nm + 32];
    }
    float bz3a = bvx[nm]      + zzv[b * 64 + nm];
    float bz3b = bvx[nm + 32] + zzv[b * 64 + nm + 32];

    float* mo = (float*)ubuf + wid2 * (15 * MOSTRIDE);
    float Aacc = 0.f, Bacc = 0.f;

    #pragma unroll 1
    for (int sub = 0; sub < 2; ++sub) {
        int pn = q0 + wid2 * 2 + sub;
        float4 g0l = *(const float4*)&xg_s[wid2][sub][0][0];
        float4 g0h = *(const float4*)&xg_s[wid2][sub][0][4];
        float g0[8] = {g0l.x, g0l.y, g0l.z, g0l.w, g0h.x, g0h.y, g0h.z, g0h.w};

        // stage 1: moments (mean over d folded as exact *0.125)
        #pragma unroll
        for (int pp = 0; pp < 4; ++pp) {
            int rg = lane >> 4;
            int r  = pp * 4 + rg;
            int rc = (r < 14) ? r : 14;
            int i2  = rc + 1;
            int i3a = (rc < 14) ? 1 : 2;
            int i3b = (rc < 14) ? rc + 2 : 3;
            float4 a1 = *(const float4*)&xg_s[wid2][sub][i2][0];
            float4 b1 = *(const float4*)&xg_s[wid2][sub][i2][4];
            float4 aa = *(const float4*)&xg_s[wid2][sub][i3a][0];
            float4 ba = *(const float4*)&xg_s[wid2][sub][i3a][4];
            float4 ab = *(const float4*)&xg_s[wid2][sub][i3b][0];
            float4 bb = *(const float4*)&xg_s[wid2][sub][i3b][4];
            float G1[8]  = {a1.x, a1.y, a1.z, a1.w, b1.x, b1.y, b1.z, b1.w};
            float G3a[8] = {aa.x, aa.y, aa.z, aa.w, ba.x, ba.y, ba.z, ba.w};
            float G3b[8] = {ab.x, ab.y, ab.z, ab.w, bb.x, bb.y, bb.z, bb.w};
            float s2 = 0.f, s3 = 0.f, t2 = 0.f, t3 = 0.f;
            #pragma unroll
            for (int d = 0; d < 8; ++d) {
                float gz = g0[d], g1 = G1[d], ga = G3a[d], gb = G3b[d];
                float y2 = fmaf(gz, w20, fmaf(g1, w21, bb2));
                s2 += fmaxf(y2, 0.f);
                float y3 = fmaf(gz, w30, fmaf(ga, w31, fmaf(gb, w32, bb3)));
                s3 += fmaxf(y3, 0.f);
                float z2 = fmaf(gz, u20, fmaf(g1, u21, cc2));
                t2 += fmaxf(z2, 0.f);
                float z3 = fmaf(gz, u30, fmaf(ga, u31, fmaf(gb, u32, cc3)));
                t3 += fmaxf(z3, 0.f);
            }
            if (r < 15) {
                mo[r * MOSTRIDE + k]      = s2 * 0.125f;
                mo[r * MOSTRIDE + 16 + k] = s3 * 0.125f;
                mo[r * MOSTRIDE + 32 + k] = t2 * 0.125f;
                mo[r * MOSTRIDE + 48 + k] = t3 * 0.125f;
            }
        }

        // stage 2: x head (packed fma over c-pairs)
        float xa = 0.f;
        #pragma unroll
        for (int half = 0; half < 2; ++half) {
            int r   = (lane >> 3) + half * 8;
            int doo = lane & 7;
            if (r < 15) {
                const f32x2* vp = (const f32x2*)&mo[r * MOSTRIDE];
                const f32x2* wp = (const f32x2*)&wmxT_s[doo][0];
                f32x2 acc = {0.f, 0.f};
                #pragma unroll
                for (int cc = 0; cc < 16; ++cc) acc = pk_fma(vp[cc], wp[cc], acc);
                float s = bzm_s[doo] + acc.x + acc.y;
                xa += fmaxf(s, 0.f);
            }
        }
        xa += __shfl_xor(xa, 8);
        xa += __shfl_xor(xa, 16);
        xa += __shfl_xor(xa, 32);
        if (lane < 8) xout[(long)pn * 8 + lane] = xa * (1.0f / 15.0f);

        // stage 3: z head (packed, half-wave row split; accumulate across sub)
        #pragma unroll 1
        for (int rr = 0; rr < 8; ++rr) {
            int r = g * 8 + rr;
            if (r < 15) {
                const f32x2* vp = (const f32x2*)&mo[r * MOSTRIDE + 32];
                f32x2 accA = {0.f, 0.f}, accB = {0.f, 0.f};
                #pragma unroll
                for (int cc = 0; cc < 16; ++cc) {
                    f32x2 v = vp[cc];
                    accA = pk_fma(v, wa2[cc], accA);
                    accB = pk_fma(v, wb2[cc], accB);
                }
                float sa = bz3a + accA.x + accA.y;
                float sb = bz3b + accB.x + accB.y;
                Aacc += fmaxf(sa, 0.f);
                Bacc += fmaxf(sb, 0.f);
            }
        }
    }

    Aacc += __shfl_xor(Aacc, 32);
    Bacc += __shfl_xor(Bacc, 32);
    float za = ((g == 0) ? Aacc : Bacc) * (1.0f / 61440.0f);
    atomicAdd(&zout[b * 64 + lane], za);      // lane = g*32+nm = output index
}

// ---------- launcher ----------

extern "C" void kernel_launch(void* const* d_in, const int* in_sizes, int n_in,
                              void* d_out, int out_size, void* d_ws, size_t ws_size,
                              hipStream_t stream) {
    const float* x   = (const float*)d_in[0];
    const float* z   = (const float*)d_in[1];
    const float* Wm2 = (const float*)d_in[2];
    const float* bm2 = (const float*)d_in[3];
    const float* Wm3 = (const float*)d_in[4];
    const float* bm3 = (const float*)d_in[5];
    const float* Wv2 = (const float*)d_in[6];
    const float* bv2 = (const float*)d_in[7];
    const float* Wv3 = (const float*)d_in[8];
    const float* bv3 = (const float*)d_in[9];
    const float* Wmx = (const float*)d_in[10];
    const float* bmx = (const float*)d_in[11];
    const float* Wvx = (const float*)d_in[12];
    const float* bvx = (const float*)d_in[13];
    const float* Wmz = (const float*)d_in[14];
    const float* bmz = (const float*)d_in[15];
    const float* Wvz = (const float*)d_in[16];
    const float* bvz = (const float*)d_in[17];

    float* out  = (float*)d_out;
    float* zzm  = (float*)d_ws;                 // 32 floats
    float* zzv  = zzm + 32;                     // 256 floats
    float* n2t  = zzv + 256;                    // 16384 floats
    float* xout = out;                          // B*NP*8 = 131072 floats
    float* zout = out + BB * NPP * 8;           // B*64 = 256 floats

    n2_kernel<<<dim3(BB * NPP / 256), dim3(256), 0, stream>>>(
        x, z, Wmz, bmz, Wvz, bvz, n2t, zzm, zzv, zout);
    fused_kernel<<<dim3(BB * NPP / NQ), dim3(128), 0, stream>>>(
        x, n2t, Wm2, bm2, Wm3, bm3, Wv2, bv2, Wv3, bv3,
        Wmx, bmx, Wvx, bvx, zzm, zzv, xout, zout);
}

// Round 11
// 255.008 us; speedup vs baseline: 1.1490x; 1.1490x over previous
//
#include <hip/hip_runtime.h>
#include <hip/hip_bf16.h>

#define NPP 4096
#define BB 4
#define NQ 4
#define CAP 128
#define MOSTRIDE 66

typedef float f32x2 __attribute__((ext_vector_type(2)));
typedef unsigned long long u64;

// packed fp32 fma: d = a*b + c elementwise on a 2-wide register pair.
__device__ __forceinline__ f32x2 pk_fma(f32x2 a, f32x2 b, f32x2 c) {
    f32x2 d;
    asm("v_pk_fma_f32 %0, %1, %2, %3" : "=v"(d) : "v"(a), "v"(b), "v"(c));
    return d;
}

template <typename T>
__device__ __forceinline__ T bitonic_sort64(T v, int lane) {
    #pragma unroll
    for (int k = 2; k <= 64; k <<= 1) {
        #pragma unroll
        for (int j = k >> 1; j > 0; j >>= 1) {
            T p = __shfl_xor(v, j);
            bool up  = ((lane & k) == 0);
            bool low = ((lane & j) == 0);
            T mn = (v < p) ? v : p;
            T mx = (v < p) ? p : v;
            v = (up == low) ? mn : mx;
        }
    }
    return v;
}

// dot8 via 4 packed fmas + horizontal add. Deterministic expression tree:
// identical in pass A and pass B -> identical key bits.
__device__ __forceinline__ float dot8_pk(const f32x2* qp, float4 A0, float4 A1) {
    f32x2 p0 = {A0.x, A0.y}, p1 = {A0.z, A0.w};
    f32x2 p2 = {A1.x, A1.y}, p3 = {A1.z, A1.w};
    f32x2 acc = {0.f, 0.f};
    acc = pk_fma(qp[0], p0, acc);
    acc = pk_fma(qp[1], p1, acc);
    acc = pk_fma(qp[2], p2, acc);
    acc = pk_fma(qp[3], p3, acc);
    return acc.x + acc.y;
}

// ---------- kernel 0: squared norms + z projections + zero zout ----------

__global__ __launch_bounds__(256) void n2_kernel(
    const float* __restrict__ x, const float* __restrict__ z,
    const float* __restrict__ Wmz, const float* __restrict__ bmz,
    const float* __restrict__ Wvz, const float* __restrict__ bvz,
    float* __restrict__ n2tab, float* __restrict__ zzm, float* __restrict__ zzv,
    float* __restrict__ zout)
{
    int i = blockIdx.x * 256 + threadIdx.x;       // 0..16383
    const float4* p = (const float4*)(x + (long)i * 8);
    float4 a = p[0], c = p[1];
    float s = 0.f;
    s = fmaf(a.x, a.x, s); s = fmaf(a.y, a.y, s);
    s = fmaf(a.z, a.z, s); s = fmaf(a.w, a.w, s);
    s = fmaf(c.x, c.x, s); s = fmaf(c.y, c.y, s);
    s = fmaf(c.z, c.z, s); s = fmaf(c.w, c.w, s);
    n2tab[i] = s;

    if (blockIdx.x == 0) {
        zout[threadIdx.x] = 0.f;                  // 256 floats
        int b = threadIdx.x >> 6, l = threadIdx.x & 63;
        float sv = 0.f;
        for (int q = 0; q < 64; ++q) sv = fmaf(z[b * 64 + q], Wvz[q * 64 + l], sv);
        zzv[b * 64 + l] = sv + bvz[l];
        if (threadIdx.x < 32) {
            int bm = threadIdx.x >> 3, lm = threadIdx.x & 7;
            float sm = 0.f;
            for (int q = 0; q < 64; ++q) sm = fmaf(z[bm * 64 + q], Wmz[q * 8 + lm], sm);
            zzm[bm * 8 + lm] = sm + bmz[lm];
        }
    }
}

// ---------- fused kernel: 1 wave per block, 4 queries per wave ----------
// Pass A (half-sampled, even t): per-lane u32 key min over 32-row disjoint
// substreams; T = 16th smallest of the 64 lane minima -> 16 distinct non-self
// witnesses <= T, so {key <= T} contains the exact top-16. (Self rows: even
// selfT patched; odd selfT never sampled in pass A.) Negative-d2 keys are
// >= 0x80000000 -> auto-excluded (reference maps d2<=0 to BIG as well).
// Pass B: full scan, predicated LDS atomic append of (key<<32)|j; u64 bitonic
// sort (+rare 2-chunk merge) -> exact sorted top-16, reference tie order.
// Everything is wave-private: NO barriers anywhere (in-order per-wave LDS).

__global__ __launch_bounds__(64) void fused_kernel(
    const float* __restrict__ x, const float* __restrict__ n2tab,
    const float* __restrict__ Wm2, const float* __restrict__ bm2,
    const float* __restrict__ Wm3, const float* __restrict__ bm3,
    const float* __restrict__ Wv2, const float* __restrict__ bv2,
    const float* __restrict__ Wv3, const float* __restrict__ bv3,
    const float* __restrict__ Wmx, const float* __restrict__ bmx,
    const float* __restrict__ Wvx, const float* __restrict__ bvx,
    const float* __restrict__ zzm, const float* __restrict__ zzv,
    float* __restrict__ xout, float* __restrict__ zout)
{
    // union: cand u64[NQ][CAP] (4096B), then mo float[15][66] (3960B)
    __shared__ __align__(16) char ubuf[4352];
    __shared__ float xg_s[NQ][16][8];         // gathered neighbors (2 KB)
    __shared__ float wmxT_s[8][36];           // Wmx transposed, 16B rows
    __shared__ float bzm_s[8];
    __shared__ unsigned cnt_s[NQ];

    int lane = threadIdx.x;                   // block = 1 wave
    int q0   = blockIdx.x * NQ;
    int b    = q0 >> 12;
    int qloc = q0 & 4095;
    const float* xb = x + (long)b * NPP * 8;
    const float* nb = n2tab + b * NPP;

    #pragma unroll
    for (int i = 0; i < 4; ++i) {
        int e = lane + i * 64;                // 0..255
        wmxT_s[e & 7][e >> 3] = Wmx[e];
    }
    if (lane < 8)  bzm_s[lane] = bmx[lane] + zzm[b * 8 + lane];
    if (lane < NQ) cnt_s[lane] = 0;

    // ---- queries ----
    f32x2 qp[NQ][4];
    float n2i[NQ];
    int selfT[NQ], selfL[NQ];
    #pragma unroll
    for (int q = 0; q < NQ; ++q) {
        const f32x2* qsrc = (const f32x2*)(xb + (long)(qloc + q) * 8);
        #pragma unroll
        for (int e = 0; e < 4; ++e) qp[q][e] = qsrc[e];
        n2i[q]   = nb[qloc + q];
        selfT[q] = (qloc + q) >> 6;
        selfL[q] = (qloc + q) & 63;
    }

    // ---- pass A: half-sampled per-lane key min ----
    unsigned minb[NQ];
    #pragma unroll
    for (int q = 0; q < NQ; ++q) minb[q] = 0xFFFFFFFFu;

    #pragma unroll 4
    for (int i = 0; i < 32; ++i) {
        int t = i << 1;
        int j = t * 64 + lane;
        const float4* pj = (const float4*)(xb + (long)j * 8);
        float4 A0 = pj[0], A1 = pj[1];
        float n2j = nb[j];
        #pragma unroll
        for (int q = 0; q < NQ; ++q) {
            float dot = dot8_pk(qp[q], A0, A1);
            float d2  = fmaf(-2.0f, dot, n2i[q] + n2j);
            unsigned kb = __float_as_uint(d2);       // d2<0 -> >=0x80000000
            if (t == selfT[q]) kb = (lane == selfL[q]) ? 0xFFFFFFFFu : kb;
            minb[q] = (kb < minb[q]) ? kb : minb[q];
        }
    }

    unsigned T[NQ];
    #pragma unroll
    for (int q = 0; q < NQ; ++q) {
        unsigned s = bitonic_sort64(minb[q], lane);
        T[q] = (unsigned)__shfl((int)s, 15);
    }

    // ---- pass B: full scan + rare predicated atomic append ----
    u64* cand = (u64*)ubuf;                   // [q*CAP + i]
    #pragma unroll 4
    for (int t = 0; t < 64; ++t) {
        int j = t * 64 + lane;
        const float4* pj = (const float4*)(xb + (long)j * 8);
        float4 A0 = pj[0], A1 = pj[1];
        float n2j = nb[j];
        #pragma unroll
        for (int q = 0; q < NQ; ++q) {
            float dot = dot8_pk(qp[q], A0, A1);
            float d2  = fmaf(-2.0f, dot, n2i[q] + n2j);
            unsigned kb = __float_as_uint(d2);
            if (t == selfT[q]) kb = (lane == selfL[q]) ? 0xFFFFFFFFu : kb;
            if (kb <= T[q]) {
                unsigned old = atomicAdd(&cnt_s[q], 1u);
                if (old < CAP) cand[q * CAP + old] = ((u64)kb << 32) | (unsigned)j;
            }
        }
    }

    // ---- sort candidates, gather top-16 neighbors (append order irrelevant) ----
    #pragma unroll 1
    for (int q = 0; q < NQ; ++q) {
        unsigned nc = cnt_s[q];
        int n = nc > CAP ? CAP : (int)nc;
        u64 v = (lane < n) ? cand[q * CAP + lane] : ~0ull;
        u64 R = bitonic_sort64(v, lane);
        if (n > 64) {                                   // rare (~1% of queries)
            u64 w2 = (64 + lane < n) ? cand[q * CAP + 64 + lane] : ~0ull;
            w2 = bitonic_sort64(w2, lane);
            u64 vt = __shfl(w2, lane - 16);
            u64 comb = (lane < 16) ? R : ((lane < 32) ? vt : ~0ull);
            R = bitonic_sort64(comb, lane);
        }
        if (lane < 16) {                      // gather issued immediately
            int id = (int)(R & 0xFFFFFFFFull);
            const float4* ps = (const float4*)(xb + (long)id * 8);
            float4 A = ps[0], C = ps[1];
            *((float4*)&xg_s[q][lane][0]) = A;
            *((float4*)&xg_s[q][lane][4]) = C;
        }
    }

    // ---- feature weights ----
    int k = lane & 15;
    float w20 = Wm2[k], w21 = Wm2[16 + k], bb2 = bm2[k];
    float w30 = Wm3[k], w31 = Wm3[16 + k], w32 = Wm3[32 + k], bb3 = bm3[k];
    float u20 = Wv2[k], u21 = Wv2[16 + k], cc2 = bv2[k];
    float u30 = Wv3[k], u31 = Wv3[16 + k], u32 = Wv3[32 + k], cc3 = bv3[k];

    int g  = lane >> 5;
    int nm = lane & 31;
    f32x2 wa2[16], wb2[16];
    #pragma unroll
    for (int cc = 0; cc < 16; ++cc) {
        wa2[cc].x = Wvx[(2 * cc) * 64 + nm];
        wa2[cc].y = Wvx[(2 * cc + 1) * 64 + nm];
        wb2[cc].x = Wvx[(2 * cc) * 64 + nm + 32];
        wb2[cc].y = Wvx[(2 * cc + 1) * 64 + nm + 32];
    }
    float bz3a = bvx[nm]      + zzv[b * 64 + nm];
    float bz3b = bvx[nm + 32] + zzv[b * 64 + nm + 32];

    // mo aliases cand: all cand LDS reads precede mo writes in program order,
    // and per-wave LDS is processed in order -> safe without a barrier.
    float* mo = (float*)ubuf;                 // [r*MOSTRIDE + c]
    float Aacc = 0.f, Bacc = 0.f;

    #pragma unroll 1
    for (int p = 0; p < NQ; ++p) {
        int pn = q0 + p;
        float4 g0l = *(const float4*)&xg_s[p][0][0];
        float4 g0h = *(const float4*)&xg_s[p][0][4];
        float g0[8] = {g0l.x, g0l.y, g0l.z, g0l.w, g0h.x, g0h.y, g0h.z, g0h.w};

        // stage 1: moments (mean over d folded as exact *0.125)
        #pragma unroll
        for (int pp = 0; pp < 4; ++pp) {
            int rg = lane >> 4;
            int r  = pp * 4 + rg;
            int rc = (r < 14) ? r : 14;
            int i2  = rc + 1;
            int i3a = (rc < 14) ? 1 : 2;
            int i3b = (rc < 14) ? rc + 2 : 3;
            float4 a1 = *(const float4*)&xg_s[p][i2][0];
            float4 b1 = *(const float4*)&xg_s[p][i2][4];
            float4 aa = *(const float4*)&xg_s[p][i3a][0];
            float4 ba = *(const float4*)&xg_s[p][i3a][4];
            float4 ab = *(const float4*)&xg_s[p][i3b][0];
            float4 bb = *(const float4*)&xg_s[p][i3b][4];
            float G1[8]  = {a1.x, a1.y, a1.z, a1.w, b1.x, b1.y, b1.z, b1.w};
            float G3a[8] = {aa.x, aa.y, aa.z, aa.w, ba.x, ba.y, ba.z, ba.w};
            float G3b[8] = {ab.x, ab.y, ab.z, ab.w, bb.x, bb.y, bb.z, bb.w};
            float s2 = 0.f, s3 = 0.f, t2 = 0.f, t3 = 0.f;
            #pragma unroll
            for (int d = 0; d < 8; ++d) {
                float gz = g0[d], g1 = G1[d], ga = G3a[d], gb = G3b[d];
                float y2 = fmaf(gz, w20, fmaf(g1, w21, bb2));
                s2 += fmaxf(y2, 0.f);
                float y3 = fmaf(gz, w30, fmaf(ga, w31, fmaf(gb, w32, bb3)));
                s3 += fmaxf(y3, 0.f);
                float z2 = fmaf(gz, u20, fmaf(g1, u21, cc2));
                t2 += fmaxf(z2, 0.f);
                float z3 = fmaf(gz, u30, fmaf(ga, u31, fmaf(gb, u32, cc3)));
                t3 += fmaxf(z3, 0.f);
            }
            if (r < 15) {
                mo[r * MOSTRIDE + k]      = s2 * 0.125f;
                mo[r * MOSTRIDE + 16 + k] = s3 * 0.125f;
                mo[r * MOSTRIDE + 32 + k] = t2 * 0.125f;
                mo[r * MOSTRIDE + 48 + k] = t3 * 0.125f;
            }
        }

        // stage 2: x head (packed fma over c-pairs)
        float xa = 0.f;
        #pragma unroll
        for (int half = 0; half < 2; ++half) {
            int r   = (lane >> 3) + half * 8;
            int doo = lane & 7;
            if (r < 15) {
                const f32x2* vp = (const f32x2*)&mo[r * MOSTRIDE];
                const f32x2* wp = (const f32x2*)&wmxT_s[doo][0];
                f32x2 acc = {0.f, 0.f};
                #pragma unroll
                for (int cc = 0; cc < 16; ++cc) acc = pk_fma(vp[cc], wp[cc], acc);
                float s = bzm_s[doo] + acc.x + acc.y;
                xa += fmaxf(s, 0.f);
            }
        }
        xa += __shfl_xor(xa, 8);
        xa += __shfl_xor(xa, 16);
        xa += __shfl_xor(xa, 32);
        if (lane < 8) xout[(long)pn * 8 + lane] = xa * (1.0f / 15.0f);

        // stage 3: z head (packed, half-wave row split; accumulate across p)
        #pragma unroll 1
        for (int rr = 0; rr < 8; ++rr) {
            int r = g * 8 + rr;
            if (r < 15) {
                const f32x2* vp = (const f32x2*)&mo[r * MOSTRIDE + 32];
                f32x2 accA = {0.f, 0.f}, accB = {0.f, 0.f};
                #pragma unroll
                for (int cc = 0; cc < 16; ++cc) {
                    f32x2 v = vp[cc];
                    accA = pk_fma(v, wa2[cc], accA);
                    accB = pk_fma(v, wb2[cc], accB);
                }
                float sa = bz3a + accA.x + accA.y;
                float sb = bz3b + accB.x + accB.y;
                Aacc += fmaxf(sa, 0.f);
                Bacc += fmaxf(sb, 0.f);
            }
        }
    }

    Aacc += __shfl_xor(Aacc, 32);
    Bacc += __shfl_xor(Bacc, 32);
    float za = ((g == 0) ? Aacc : Bacc) * (1.0f / 61440.0f);
    atomicAdd(&zout[b * 64 + lane], za);      // lane = g*32+nm = output index
}

// ---------- launcher ----------

extern "C" void kernel_launch(void* const* d_in, const int* in_sizes, int n_in,
                              void* d_out, int out_size, void* d_ws, size_t ws_size,
                              hipStream_t stream) {
    const float* x   = (const float*)d_in[0];
    const float* z   = (const float*)d_in[1];
    const float* Wm2 = (const float*)d_in[2];
    const float* bm2 = (const float*)d_in[3];
    const float* Wm3 = (const float*)d_in[4];
    const float* bm3 = (const float*)d_in[5];
    const float* Wv2 = (const float*)d_in[6];
    const float* bv2 = (const float*)d_in[7];
    const float* Wv3 = (const float*)d_in[8];
    const float* bv3 = (const float*)d_in[9];
    const float* Wmx = (const float*)d_in[10];
    const float* bmx = (const float*)d_in[11];
    const float* Wvx = (const float*)d_in[12];
    const float* bvx = (const float*)d_in[13];
    const float* Wmz = (const float*)d_in[14];
    const float* bmz = (const float*)d_in[15];
    const float* Wvz = (const float*)d_in[16];
    const float* bvz = (const float*)d_in[17];

    float* out  = (float*)d_out;
    float* zzm  = (float*)d_ws;                 // 32 floats
    float* zzv  = zzm + 32;                     // 256 floats
    float* n2t  = zzv + 256;                    // 16384 floats
    float* xout = out;                          // B*NP*8 = 131072 floats
    float* zout = out + BB * NPP * 8;           // B*64 = 256 floats

    n2_kernel<<<dim3(BB * NPP / 256), dim3(256), 0, stream>>>(
        x, z, Wmz, bmz, Wvz, bvz, n2t, zzm, zzv, zout);
    fused_kernel<<<dim3(BB * NPP / NQ), dim3(64), 0, stream>>>(
        x, n2t, Wm2, bm2, Wm3, bm3, Wv2, bv2, Wv3, bv3,
        Wmx, bmx, Wvx, bvx, zzm, zzv, xout, zout);
}